// Round 5
// baseline (850.874 us; speedup 1.0000x reference)
//
#include <hip/hip_runtime.h>
#include <hip/hip_bf16.h>

#define HF 96   // feature/hidden dim
#define GG 64
#define SB 64   // scan blocks per direction

// ---------------- degree counts + slot assignment ----------------
__global__ void count_kernel(const int* __restrict__ ei, int* __restrict__ cnt_dst,
                             int* __restrict__ cnt_src, int* __restrict__ slot_d,
                             int* __restrict__ slot_s, int E) {
    int e = blockIdx.x * blockDim.x + threadIdx.x;
    if (e >= E) return;
    int s = ei[e];
    int d = ei[E + e];
    slot_d[e] = atomicAdd(&cnt_dst[d], 1);
    slot_s[e] = atomicAdd(&cnt_src[s], 1);
}

// ---------------- 3-phase exclusive scan ----------------
__global__ __launch_bounds__(256) void scan_phase1(const int* __restrict__ cnt0,
                                                   const int* __restrict__ cnt1,
                                                   int* __restrict__ off0,
                                                   int* __restrict__ off1,
                                                   int* __restrict__ bsum, int N, int CH) {
    int dir = blockIdx.y;
    const int* cnt = dir ? cnt1 : cnt0;
    int* off = dir ? off1 : off0;
    int base = blockIdx.x * CH;
    int end = base + CH; if (end > N) end = N;
    __shared__ int buf[256];
    int carry = 0;
    for (int s = base; s < end; s += 256) {
        int i = s + threadIdx.x;
        int v = (i < end) ? cnt[i] : 0;
        buf[threadIdx.x] = v;
        __syncthreads();
        for (int st = 1; st < 256; st <<= 1) {
            int tv = (threadIdx.x >= st) ? buf[threadIdx.x - st] : 0;
            __syncthreads();
            buf[threadIdx.x] += tv;
            __syncthreads();
        }
        if (i < end) off[i] = carry + buf[threadIdx.x] - v;
        carry += buf[255];
        __syncthreads();
    }
    if (threadIdx.x == 0) bsum[dir * SB + blockIdx.x] = carry;
}

__global__ __launch_bounds__(64) void scan_phase2(int* __restrict__ bsum, int* __restrict__ boff,
                                                  int* __restrict__ off0, int* __restrict__ off1,
                                                  int N) {
    int dir = blockIdx.x;
    __shared__ int buf[SB];
    int v = bsum[dir * SB + threadIdx.x];
    buf[threadIdx.x] = v;
    __syncthreads();
    for (int st = 1; st < SB; st <<= 1) {
        int tv = (threadIdx.x >= st) ? buf[threadIdx.x - st] : 0;
        __syncthreads();
        buf[threadIdx.x] += tv;
        __syncthreads();
    }
    boff[dir * SB + threadIdx.x] = buf[threadIdx.x] - v;
    if (threadIdx.x == SB - 1) {
        int* off = dir ? off1 : off0;
        off[N] = buf[SB - 1];
    }
}

__global__ void scan_phase3(int* __restrict__ off0, int* __restrict__ off1,
                            const int* __restrict__ boff, int N, int CH) {
    int dir = blockIdx.y;
    int* off = dir ? off1 : off0;
    int i = blockIdx.x * 256 + threadIdx.x;
    if (i >= N) return;
    off[i] += boff[dir * SB + i / CH];
}

// ---------------- CSR fill (atomic-free: slots precomputed) ----------------
__global__ void fill_kernel(const int* __restrict__ ei, const int* __restrict__ off_dst,
                            const int* __restrict__ off_src, const int* __restrict__ slot_d,
                            const int* __restrict__ slot_s, int* __restrict__ nbr_dst,
                            int* __restrict__ nbr_src, int E) {
    int e = blockIdx.x * blockDim.x + threadIdx.x;
    if (e >= E) return;
    int s = ei[e];
    int d = ei[E + e];
    nbr_dst[off_dst[d] + slot_d[e]] = s;
    nbr_src[off_src[s] + slot_s[e]] = d;
}

// ---------------- weight prep: Wt[j][mk] = W_m[k][j] (96x288), bc = combined bias ----------------
__global__ void prep_kernel(const float* __restrict__ Wself, const float* __restrict__ Wsd,
                            const float* __restrict__ Wds, const float* __restrict__ bself,
                            const float* __restrict__ bsd, const float* __restrict__ bds,
                            float* __restrict__ Wt, float* __restrict__ bc) {
    int idx = blockIdx.x * 256 + threadIdx.x;
    if (idx < HF * 288) {
        int kk = idx % 288;
        int j = idx / 288;
        int m = kk / HF, k = kk % HF;
        const float* W = (m == 0) ? Wself : (m == 1) ? Wsd : Wds;
        Wt[idx] = W[k * HF + j];
    } else if (idx < HF * 288 + HF) {
        int j = idx - HF * 288;
        bc[j] = bself[j] + 0.5f * (bsd[j] + bds[j]);
    }
}

// ---------------- gather-mean (x0.5 ALPHA folded), direction-split, 4-way unrolled ----------------
__global__ __launch_bounds__(256) void gather_kernel(
        const float* __restrict__ x,
        const int* __restrict__ off_dst, const int* __restrict__ nbr_dst,
        const int* __restrict__ off_src, const int* __restrict__ nbr_src,
        float* __restrict__ agg_sd, float* __restrict__ agg_ds, int N) {
    int t = blockIdx.x * blockDim.x + threadIdx.x;
    int n2 = t / 24;
    if (n2 >= 2 * N) return;
    int q = t % 24;
    int dir = (n2 >= N) ? 1 : 0;
    int n = n2 - dir * N;
    const int* off = dir ? off_src : off_dst;
    const int* nbr = dir ? nbr_src : nbr_dst;
    float* agg = dir ? agg_ds : agg_sd;

    int b = off[n], e = off[n + 1];
    const float* xq = x + q * 4;
    float4 a0 = make_float4(0.f, 0.f, 0.f, 0.f);
    float4 a1 = make_float4(0.f, 0.f, 0.f, 0.f);
    float4 a2 = make_float4(0.f, 0.f, 0.f, 0.f);
    float4 a3 = make_float4(0.f, 0.f, 0.f, 0.f);
    int i = b;
    for (; i + 4 <= e; i += 4) {
        int i0 = nbr[i + 0], i1 = nbr[i + 1], i2 = nbr[i + 2], i3 = nbr[i + 3];
        float4 v0 = *(const float4*)(xq + (long long)i0 * HF);
        float4 v1 = *(const float4*)(xq + (long long)i1 * HF);
        float4 v2 = *(const float4*)(xq + (long long)i2 * HF);
        float4 v3 = *(const float4*)(xq + (long long)i3 * HF);
        a0.x += v0.x; a0.y += v0.y; a0.z += v0.z; a0.w += v0.w;
        a1.x += v1.x; a1.y += v1.y; a1.z += v1.z; a1.w += v1.w;
        a2.x += v2.x; a2.y += v2.y; a2.z += v2.z; a2.w += v2.w;
        a3.x += v3.x; a3.y += v3.y; a3.z += v3.z; a3.w += v3.w;
    }
    for (; i < e; i++) {
        int i0 = nbr[i];
        float4 v0 = *(const float4*)(xq + (long long)i0 * HF);
        a0.x += v0.x; a0.y += v0.y; a0.z += v0.z; a0.w += v0.w;
    }
    float4 acc;
    acc.x = (a0.x + a1.x) + (a2.x + a3.x);
    acc.y = (a0.y + a1.y) + (a2.y + a3.y);
    acc.z = (a0.z + a1.z) + (a2.z + a3.z);
    acc.w = (a0.w + a1.w) + (a2.w + a3.w);
    float inv = 0.5f / fmaxf((float)(e - b), 1.0f);   // ALPHA=0.5 folded (exact pow2 scale)
    acc.x *= inv; acc.y *= inv; acc.z *= inv; acc.w *= inv;
    *(float4*)(agg + (long long)n * HF + q * 4) = acc;
}

// ---------------- sage GEMM v2: row-per-lane, scalar (SGPR) weights, no LDS ----------------
// C[N x 96] = relu([x | agg_sd | agg_ds] @ Wt^T + bc); Wt is [96][288] col-major-by-k.
// grid (ceil(N/256), 4): blockIdx.y = column quarter (24 cols), lane = row.
__global__ __launch_bounds__(256) void sage_gemm2(
        const float* __restrict__ x, const float* __restrict__ agg_sd,
        const float* __restrict__ agg_ds,
        const float* __restrict__ Wt, const float* __restrict__ bc,
        float* __restrict__ out, int N) {
    const int quarter = blockIdx.y;          // 0..3
    int r = blockIdx.x * 256 + threadIdx.x;
    int rr = (r < N) ? r : (N - 1);

    float acc[24];
#pragma unroll
    for (int j = 0; j < 24; j++) acc[j] = 0.f;

    const float* Wq = Wt + (long long)quarter * 24 * 288;

    for (int m = 0; m < 3; m++) {
        const float* Ar = ((m == 0) ? x : (m == 1) ? agg_sd : agg_ds) + (long long)rr * HF;
        for (int kc = 0; kc < HF; kc += 8) {
            float4 a0 = *(const float4*)(Ar + kc);
            float4 a1 = *(const float4*)(Ar + kc + 4);
            const float* wp0 = Wq + m * HF + kc;
#pragma unroll
            for (int j = 0; j < 24; j++) {
                const float* wp = wp0 + j * 288;   // wave-uniform address -> s_load
                float s = acc[j];
                s = fmaf(a0.x, wp[0], s);
                s = fmaf(a0.y, wp[1], s);
                s = fmaf(a0.z, wp[2], s);
                s = fmaf(a0.w, wp[3], s);
                s = fmaf(a1.x, wp[4], s);
                s = fmaf(a1.y, wp[5], s);
                s = fmaf(a1.z, wp[6], s);
                s = fmaf(a1.w, wp[7], s);
                acc[j] = s;
            }
        }
    }

    if (r < N) {
        const float* bch = bc + quarter * 24;
        float* po = out + (long long)r * HF + quarter * 24;
#pragma unroll
        for (int j4 = 0; j4 < 6; j4++) {
            float4 o;
            o.x = fmaxf(acc[j4 * 4 + 0] + bch[j4 * 4 + 0], 0.f);
            o.y = fmaxf(acc[j4 * 4 + 1] + bch[j4 * 4 + 1], 0.f);
            o.z = fmaxf(acc[j4 * 4 + 2] + bch[j4 * 4 + 2], 0.f);
            o.w = fmaxf(acc[j4 * 4 + 3] + bch[j4 * 4 + 3], 0.f);
            *(float4*)(po + j4 * 4) = o;
        }
    }
}

// ---------------- segment max pool (batch sorted) ----------------
#define POOL_CHUNK 128
__global__ void pool_kernel(const float* __restrict__ h, const int* __restrict__ batch,
                            unsigned* __restrict__ g, int N) {
    int j = threadIdx.x;
    if (j >= HF) return;
    int n0 = blockIdx.x * POOL_CHUNK;
    int end = n0 + POOL_CHUNK;
    if (end > N) end = N;
    float cur = 0.0f;
    int curb = -1;
    for (int n = n0; n < end; n++) {
        int b = batch[n];
        float v = h[(long long)n * HF + j];
        if (b != curb) {
            if (curb >= 0) atomicMax(&g[curb * HF + j], __float_as_uint(cur));
            curb = b;
            cur = v;
        } else {
            cur = fmaxf(cur, v);
        }
    }
    if (curb >= 0) atomicMax(&g[curb * HF + j], __float_as_uint(cur));
}

// ---------------- final MLP ----------------
__global__ void mlp_kernel(const unsigned* __restrict__ g, const float* __restrict__ lin1_w,
                           const float* __restrict__ lin1_b, const float* __restrict__ lin2_w,
                           const float* __restrict__ lin2_b, float* __restrict__ out) {
    int gi = threadIdx.x;
    if (gi >= GG) return;
    float h5[5];
#pragma unroll
    for (int hh = 0; hh < 5; hh++) {
        float acc = lin1_b[hh];
#pragma unroll 8
        for (int k = 0; k < HF; k++)
            acc = fmaf(__uint_as_float(g[gi * HF + k]), lin1_w[k * 5 + hh], acc);
        h5[hh] = fmaxf(acc, 0.0f);
    }
    float o = lin2_b[0];
#pragma unroll
    for (int hh = 0; hh < 5; hh++) o = fmaf(h5[hh], lin2_w[hh * 1 + 0], o);
    out[gi] = o;
}

extern "C" void kernel_launch(void* const* d_in, const int* in_sizes, int n_in,
                              void* d_out, int out_size, void* d_ws, size_t ws_size,
                              hipStream_t stream) {
    const float* x     = (const float*)d_in[0];
    const int*   ei    = (const int*)d_in[1];
    const int*   batch = (const int*)d_in[2];
    const float* W[3][3];
    const float* B[3][3];
    for (int l = 0; l < 3; l++) {
        for (int t = 0; t < 3; t++) W[l][t] = (const float*)d_in[3 + l * 6 + t];
        for (int t = 0; t < 3; t++) B[l][t] = (const float*)d_in[3 + l * 6 + 3 + t];
    }
    const float* lin1_w = (const float*)d_in[21];
    const float* lin1_b = (const float*)d_in[22];
    const float* lin2_w = (const float*)d_in[23];
    const float* lin2_b = (const float*)d_in[24];

    const int N = in_sizes[0] / HF;
    const int E = in_sizes[1] / 2;

    // workspace layout
    float* hA      = (float*)d_ws;
    float* hB      = hA + (long long)N * HF;
    float* agg_sd  = hB + (long long)N * HF;
    float* agg_ds  = agg_sd + (long long)N * HF;
    int*   cnt_dst = (int*)(agg_ds + (long long)N * HF);
    int*   cnt_src = cnt_dst + N;
    int*   off_dst = cnt_src + N;           // N+1
    int*   off_src = off_dst + (N + 1);     // N+1
    int*   nbr_dst = off_src + (N + 1);     // E
    int*   nbr_src = nbr_dst + E;           // E
    int*   slot_d  = nbr_src + E;           // E
    int*   slot_s  = slot_d + E;            // E
    int*   bsum    = slot_s + E;            // 2*SB
    int*   boff    = bsum + 2 * SB;         // 2*SB
    float* Wt3     = (float*)(boff + 2 * SB);   // 3 * 96*288
    float* bc3     = Wt3 + 3 * HF * 288;        // 3 * 96
    unsigned* g    = (unsigned*)(bc3 + 3 * HF);

    hipMemsetAsync(cnt_dst, 0, (size_t)2 * N * sizeof(int), stream);
    hipMemsetAsync(g, 0, (size_t)GG * HF * sizeof(unsigned), stream);

    // weight prep (independent of graph build)
    const int prep_blocks = (HF * 288 + HF + 255) / 256;
    for (int l = 0; l < 3; l++)
        prep_kernel<<<prep_blocks, 256, 0, stream>>>(
            W[l][0], W[l][1], W[l][2], B[l][0], B[l][1], B[l][2],
            Wt3 + (long long)l * HF * 288, bc3 + l * HF);

    const int CH = (N + SB - 1) / SB;
    count_kernel<<<(E + 255) / 256, 256, 0, stream>>>(ei, cnt_dst, cnt_src, slot_d, slot_s, E);
    scan_phase1<<<dim3(SB, 2), 256, 0, stream>>>(cnt_dst, cnt_src, off_dst, off_src, bsum, N, CH);
    scan_phase2<<<2, SB, 0, stream>>>(bsum, boff, off_dst, off_src, N);
    scan_phase3<<<dim3((N + 255) / 256, 2), 256, 0, stream>>>(off_dst, off_src, boff, N, CH);
    fill_kernel<<<(E + 255) / 256, 256, 0, stream>>>(ei, off_dst, off_src,
                                                     slot_d, slot_s, nbr_dst, nbr_src, E);

    const long long gather_threads = (long long)2 * N * 24;
    const int gather_blocks = (int)((gather_threads + 255) / 256);
    const int gemm_bx = (N + 255) / 256;
    const int pool_blocks = (N + POOL_CHUNK - 1) / POOL_CHUNK;

    const float* cur_in = x;
    float* outs[3] = { hA, hB, hA };
    for (int l = 0; l < 3; l++) {
        gather_kernel<<<gather_blocks, 256, 0, stream>>>(
            cur_in, off_dst, nbr_dst, off_src, nbr_src, agg_sd, agg_ds, N);
        sage_gemm2<<<dim3(gemm_bx, 4), 256, 0, stream>>>(
            cur_in, agg_sd, agg_ds,
            Wt3 + (long long)l * HF * 288, bc3 + l * HF,
            outs[l], N);
        cur_in = outs[l];
    }

    pool_kernel<<<pool_blocks, 128, 0, stream>>>(outs[2], batch, g, N);
    mlp_kernel<<<1, 64, 0, stream>>>(g, lin1_w, lin1_b, lin2_w, lin2_b, (float*)d_out);
}

// Round 7
// 561.705 us; speedup vs baseline: 1.5148x; 1.5148x over previous
//
#include <hip/hip_runtime.h>
#include <hip/hip_bf16.h>

#define HF 96   // feature/hidden dim
#define GG 64
#define SB 64   // scan blocks per direction

typedef __attribute__((ext_vector_type(8))) short bf16x8;
typedef __attribute__((ext_vector_type(4))) float f32x4;

__device__ __forceinline__ unsigned short f2bf(float f) {
    unsigned u = __float_as_uint(f);
    unsigned r = (u + 0x7FFFu + ((u >> 16) & 1u)) >> 16;
    return (unsigned short)r;
}
__device__ __forceinline__ float bf2f(unsigned short h) {
    return __uint_as_float(((unsigned)h) << 16);
}

// ---------------- degree counts + slot assignment ----------------
__global__ void count_kernel(const int* __restrict__ ei, int* __restrict__ cnt_dst,
                             int* __restrict__ cnt_src, int* __restrict__ slot_d,
                             int* __restrict__ slot_s, int E) {
    int e = blockIdx.x * blockDim.x + threadIdx.x;
    if (e >= E) return;
    int s = ei[e];
    int d = ei[E + e];
    slot_d[e] = atomicAdd(&cnt_dst[d], 1);
    slot_s[e] = atomicAdd(&cnt_src[s], 1);
}

// ---------------- 3-phase exclusive scan ----------------
__global__ __launch_bounds__(256) void scan_phase1(const int* __restrict__ cnt0,
                                                   const int* __restrict__ cnt1,
                                                   int* __restrict__ off0,
                                                   int* __restrict__ off1,
                                                   int* __restrict__ bsum, int N, int CH) {
    int dir = blockIdx.y;
    const int* cnt = dir ? cnt1 : cnt0;
    int* off = dir ? off1 : off0;
    int base = blockIdx.x * CH;
    int end = base + CH; if (end > N) end = N;
    __shared__ int buf[256];
    int carry = 0;
    for (int s = base; s < end; s += 256) {
        int i = s + threadIdx.x;
        int v = (i < end) ? cnt[i] : 0;
        buf[threadIdx.x] = v;
        __syncthreads();
        for (int st = 1; st < 256; st <<= 1) {
            int tv = (threadIdx.x >= st) ? buf[threadIdx.x - st] : 0;
            __syncthreads();
            buf[threadIdx.x] += tv;
            __syncthreads();
        }
        if (i < end) off[i] = carry + buf[threadIdx.x] - v;
        carry += buf[255];
        __syncthreads();
    }
    if (threadIdx.x == 0) bsum[dir * SB + blockIdx.x] = carry;
}

__global__ __launch_bounds__(64) void scan_phase2(int* __restrict__ bsum, int* __restrict__ boff,
                                                  int* __restrict__ off0, int* __restrict__ off1,
                                                  int N) {
    int dir = blockIdx.x;
    __shared__ int buf[SB];
    int v = bsum[dir * SB + threadIdx.x];
    buf[threadIdx.x] = v;
    __syncthreads();
    for (int st = 1; st < SB; st <<= 1) {
        int tv = (threadIdx.x >= st) ? buf[threadIdx.x - st] : 0;
        __syncthreads();
        buf[threadIdx.x] += tv;
        __syncthreads();
    }
    boff[dir * SB + threadIdx.x] = buf[threadIdx.x] - v;
    if (threadIdx.x == SB - 1) {
        int* off = dir ? off1 : off0;
        off[N] = buf[SB - 1];
    }
}

__global__ void scan_phase3(int* __restrict__ off0, int* __restrict__ off1,
                            const int* __restrict__ boff, int N, int CH) {
    int dir = blockIdx.y;
    int* off = dir ? off1 : off0;
    int i = blockIdx.x * 256 + threadIdx.x;
    if (i >= N) return;
    off[i] += boff[dir * SB + i / CH];
}

// ---------------- CSR fill (atomic-free: slots precomputed) ----------------
__global__ void fill_kernel(const int* __restrict__ ei, const int* __restrict__ off_dst,
                            const int* __restrict__ off_src, const int* __restrict__ slot_d,
                            const int* __restrict__ slot_s, int* __restrict__ nbr_dst,
                            int* __restrict__ nbr_src, int E) {
    int e = blockIdx.x * blockDim.x + threadIdx.x;
    if (e >= E) return;
    int s = ei[e];
    int d = ei[E + e];
    nbr_dst[off_dst[d] + slot_d[e]] = s;
    nbr_src[off_src[s] + slot_s[e]] = d;
}

// ---------------- weight prep: transpose + bf16 hi/lo split ----------------
// Whi/Wlo: [96][288] ushort, k-global = m*96 + k; bc = combined bias
__global__ void prep_kernel(const float* __restrict__ Wself, const float* __restrict__ Wsd,
                            const float* __restrict__ Wds, const float* __restrict__ bself,
                            const float* __restrict__ bsd, const float* __restrict__ bds,
                            unsigned short* __restrict__ Whi, unsigned short* __restrict__ Wlo,
                            float* __restrict__ bc) {
    int idx = blockIdx.x * 256 + threadIdx.x;
    if (idx < HF * 288) {
        int j = idx / 288;
        int kk = idx % 288;
        int m = kk / HF, k = kk % HF;
        const float* W = (m == 0) ? Wself : (m == 1) ? Wsd : Wds;
        float w = W[k * HF + j];
        unsigned short hi = f2bf(w);
        float rem = w - bf2f(hi);
        Whi[idx] = hi;
        Wlo[idx] = f2bf(rem);
    } else if (idx < HF * 288 + HF) {
        int j = idx - HF * 288;
        bc[j] = bself[j] + 0.5f * (bsd[j] + bds[j]);
    }
}

// ---------------- gather-mean (x0.5 ALPHA folded), direction-split, 4-way unrolled ----------------
__global__ __launch_bounds__(256) void gather_kernel(
        const float* __restrict__ x,
        const int* __restrict__ off_dst, const int* __restrict__ nbr_dst,
        const int* __restrict__ off_src, const int* __restrict__ nbr_src,
        float* __restrict__ agg_sd, float* __restrict__ agg_ds, int N) {
    int t = blockIdx.x * blockDim.x + threadIdx.x;
    int n2 = t / 24;
    if (n2 >= 2 * N) return;
    int q = t % 24;
    int dir = (n2 >= N) ? 1 : 0;
    int n = n2 - dir * N;
    const int* off = dir ? off_src : off_dst;
    const int* nbr = dir ? nbr_src : nbr_dst;
    float* agg = dir ? agg_ds : agg_sd;

    int b = off[n], e = off[n + 1];
    const float* xq = x + q * 4;
    float4 a0 = make_float4(0.f, 0.f, 0.f, 0.f);
    float4 a1 = make_float4(0.f, 0.f, 0.f, 0.f);
    float4 a2 = make_float4(0.f, 0.f, 0.f, 0.f);
    float4 a3 = make_float4(0.f, 0.f, 0.f, 0.f);
    int i = b;
    for (; i + 4 <= e; i += 4) {
        int i0 = nbr[i + 0], i1 = nbr[i + 1], i2 = nbr[i + 2], i3 = nbr[i + 3];
        float4 v0 = *(const float4*)(xq + (long long)i0 * HF);
        float4 v1 = *(const float4*)(xq + (long long)i1 * HF);
        float4 v2 = *(const float4*)(xq + (long long)i2 * HF);
        float4 v3 = *(const float4*)(xq + (long long)i3 * HF);
        a0.x += v0.x; a0.y += v0.y; a0.z += v0.z; a0.w += v0.w;
        a1.x += v1.x; a1.y += v1.y; a1.z += v1.z; a1.w += v1.w;
        a2.x += v2.x; a2.y += v2.y; a2.z += v2.z; a2.w += v2.w;
        a3.x += v3.x; a3.y += v3.y; a3.z += v3.z; a3.w += v3.w;
    }
    for (; i < e; i++) {
        int i0 = nbr[i];
        float4 v0 = *(const float4*)(xq + (long long)i0 * HF);
        a0.x += v0.x; a0.y += v0.y; a0.z += v0.z; a0.w += v0.w;
    }
    float4 acc;
    acc.x = (a0.x + a1.x) + (a2.x + a3.x);
    acc.y = (a0.y + a1.y) + (a2.y + a3.y);
    acc.z = (a0.z + a1.z) + (a2.z + a3.z);
    acc.w = (a0.w + a1.w) + (a2.w + a3.w);
    float inv = 0.5f / fmaxf((float)(e - b), 1.0f);   // ALPHA=0.5 folded (exact pow2 scale)
    acc.x *= inv; acc.y *= inv; acc.z *= inv; acc.w *= inv;
    *(float4*)(agg + (long long)n * HF + q * 4) = acc;
}

// ---------------- sage GEMM v3: MFMA bf16 hi/lo split (3-mfma fp32 emulation) ----------------
// C[N x 96] = relu([x | agg_sd | agg_ds](N x 288) @ W(288 x 96) + bc)
// block: 64 rows x 96 cols, 256 thr = 4 waves in 2x2 (wave: 32 rows x 48 cols)
// K-chunks of 32; LDS holds A(64x32) and Wt(96x32) as bf16 hi/lo, pad 40.
#define LPAD 40
__global__ __launch_bounds__(256) void sage_mfma(
        const float* __restrict__ x, const float* __restrict__ agg_sd,
        const float* __restrict__ agg_ds,
        const unsigned short* __restrict__ Whi_g, const unsigned short* __restrict__ Wlo_g,
        const float* __restrict__ bc,
        float* __restrict__ out, int N) {
    __shared__ __align__(16) unsigned short Ahi[64 * LPAD];
    __shared__ __align__(16) unsigned short Alo[64 * LPAD];
    __shared__ __align__(16) unsigned short Whi[96 * LPAD];
    __shared__ __align__(16) unsigned short Wlo[96 * LPAD];

    const int tx = threadIdx.x;
    const int lane = tx & 63;
    const int wid = tx >> 6;
    const int wr = (wid >> 1) * 32;   // wave row offset in block tile
    const int wc = (wid & 1) * 48;    // wave col offset
    const int m = lane & 15;
    const int quad = lane >> 4;
    const int row0 = blockIdx.x * 64;

    // staging indices
    const int arow = tx >> 2;         // 0..63
    const int aq = tx & 3;            // 0..3 (8 floats each)
    int argc = row0 + arow; if (argc > N - 1) argc = N - 1;

    f32x4 acc[2][3];
#pragma unroll
    for (int rt = 0; rt < 2; rt++)
#pragma unroll
        for (int ct = 0; ct < 3; ct++) acc[rt][ct] = (f32x4){0.f, 0.f, 0.f, 0.f};

    for (int kt = 0; kt < 9; kt++) {
        const float* A = (kt < 3) ? x : (kt < 6) ? agg_sd : agg_ds;
        const int koff = (kt % 3) * 32;          // k offset within the 96-wide source
        const int kglob = kt * 32;               // k offset in the 288 concat

        // ---- stage A: 64x32 fp32 -> bf16 hi/lo (1 x 8 floats per thread)
        {
            const float* Ar = A + (long long)argc * HF + koff + aq * 8;
            float4 v0 = *(const float4*)(Ar + 0);
            float4 v1 = *(const float4*)(Ar + 4);
            float f[8] = {v0.x, v0.y, v0.z, v0.w, v1.x, v1.y, v1.z, v1.w};
            bf16x8 hv, lv;
#pragma unroll
            for (int i = 0; i < 8; i++) {
                unsigned short h = f2bf(f[i]);
                hv[i] = (short)h;
                lv[i] = (short)f2bf(f[i] - bf2f(h));
            }
            *(bf16x8*)&Ahi[arow * LPAD + aq * 8] = hv;
            *(bf16x8*)&Alo[arow * LPAD + aq * 8] = lv;
        }
        // ---- stage W: 96x32 bf16 hi/lo, pre-split in global (copy 16B chunks)
        for (int s = tx; s < 384; s += 256) {
            int n = s >> 2, q2 = s & 3;
            long long go = (long long)n * 288 + kglob + q2 * 8;
            *(bf16x8*)&Whi[n * LPAD + q2 * 8] = *(const bf16x8*)(Whi_g + go);
            *(bf16x8*)&Wlo[n * LPAD + q2 * 8] = *(const bf16x8*)(Wlo_g + go);
        }
        __syncthreads();

        // ---- fragments
        bf16x8 ah[2], al[2], bh[3], bl[3];
#pragma unroll
        for (int rt = 0; rt < 2; rt++) {
            int r = (wr + rt * 16 + m) * LPAD + quad * 8;
            ah[rt] = *(const bf16x8*)&Ahi[r];
            al[rt] = *(const bf16x8*)&Alo[r];
        }
#pragma unroll
        for (int ct = 0; ct < 3; ct++) {
            int r = (wc + ct * 16 + m) * LPAD + quad * 8;
            bh[ct] = *(const bf16x8*)&Whi[r];
            bl[ct] = *(const bf16x8*)&Wlo[r];
        }
#pragma unroll
        for (int rt = 0; rt < 2; rt++)
#pragma unroll
            for (int ct = 0; ct < 3; ct++) {
                acc[rt][ct] = __builtin_amdgcn_mfma_f32_16x16x32_bf16(ah[rt], bh[ct], acc[rt][ct], 0, 0, 0);
                acc[rt][ct] = __builtin_amdgcn_mfma_f32_16x16x32_bf16(ah[rt], bl[ct], acc[rt][ct], 0, 0, 0);
                acc[rt][ct] = __builtin_amdgcn_mfma_f32_16x16x32_bf16(al[rt], bh[ct], acc[rt][ct], 0, 0, 0);
            }
        __syncthreads();
    }

    // ---- epilogue: bias + relu + store (C/D: col=lane&15, row=quad*4+reg)
#pragma unroll
    for (int ct = 0; ct < 3; ct++) {
        int col = wc + ct * 16 + m;
        float bcv = bc[col];
#pragma unroll
        for (int rt = 0; rt < 2; rt++) {
#pragma unroll
            for (int reg = 0; reg < 4; reg++) {
                int r = row0 + wr + rt * 16 + quad * 4 + reg;
                if (r < N) out[(long long)r * HF + col] = fmaxf(acc[rt][ct][reg] + bcv, 0.f);
            }
        }
    }
}

// ---------------- segment max pool (batch sorted) ----------------
#define POOL_CHUNK 128
__global__ void pool_kernel(const float* __restrict__ h, const int* __restrict__ batch,
                            unsigned* __restrict__ g, int N) {
    int j = threadIdx.x;
    if (j >= HF) return;
    int n0 = blockIdx.x * POOL_CHUNK;
    int end = n0 + POOL_CHUNK;
    if (end > N) end = N;
    float cur = 0.0f;
    int curb = -1;
    for (int n = n0; n < end; n++) {
        int b = batch[n];
        float v = h[(long long)n * HF + j];
        if (b != curb) {
            if (curb >= 0) atomicMax(&g[curb * HF + j], __float_as_uint(cur));
            curb = b;
            cur = v;
        } else {
            cur = fmaxf(cur, v);
        }
    }
    if (curb >= 0) atomicMax(&g[curb * HF + j], __float_as_uint(cur));
}

// ---------------- final MLP ----------------
__global__ void mlp_kernel(const unsigned* __restrict__ g, const float* __restrict__ lin1_w,
                           const float* __restrict__ lin1_b, const float* __restrict__ lin2_w,
                           const float* __restrict__ lin2_b, float* __restrict__ out) {
    int gi = threadIdx.x;
    if (gi >= GG) return;
    float h5[5];
#pragma unroll
    for (int hh = 0; hh < 5; hh++) {
        float acc = lin1_b[hh];
#pragma unroll 8
        for (int k = 0; k < HF; k++)
            acc = fmaf(__uint_as_float(g[gi * HF + k]), lin1_w[k * 5 + hh], acc);
        h5[hh] = fmaxf(acc, 0.0f);
    }
    float o = lin2_b[0];
#pragma unroll
    for (int hh = 0; hh < 5; hh++) o = fmaf(h5[hh], lin2_w[hh * 1 + 0], o);
    out[gi] = o;
}

extern "C" void kernel_launch(void* const* d_in, const int* in_sizes, int n_in,
                              void* d_out, int out_size, void* d_ws, size_t ws_size,
                              hipStream_t stream) {
    const float* x     = (const float*)d_in[0];
    const int*   ei    = (const int*)d_in[1];
    const int*   batch = (const int*)d_in[2];
    const float* W[3][3];
    const float* B[3][3];
    for (int l = 0; l < 3; l++) {
        for (int t = 0; t < 3; t++) W[l][t] = (const float*)d_in[3 + l * 6 + t];
        for (int t = 0; t < 3; t++) B[l][t] = (const float*)d_in[3 + l * 6 + 3 + t];
    }
    const float* lin1_w = (const float*)d_in[21];
    const float* lin1_b = (const float*)d_in[22];
    const float* lin2_w = (const float*)d_in[23];
    const float* lin2_b = (const float*)d_in[24];

    const int N = in_sizes[0] / HF;
    const int E = in_sizes[1] / 2;

    // workspace layout
    float* hA      = (float*)d_ws;
    float* hB      = hA + (long long)N * HF;
    float* agg_sd  = hB + (long long)N * HF;
    float* agg_ds  = agg_sd + (long long)N * HF;
    int*   cnt_dst = (int*)(agg_ds + (long long)N * HF);
    int*   cnt_src = cnt_dst + N;
    int*   off_dst = cnt_src + N;           // N+1
    int*   off_src = off_dst + (N + 1);     // N+1
    int*   nbr_dst = off_src + (N + 1);     // E
    int*   nbr_src = nbr_dst + E;           // E
    int*   slot_d  = nbr_src + E;           // E
    int*   slot_s  = slot_d + E;            // E
    int*   bsum    = slot_s + E;            // 2*SB
    int*   boff    = bsum + 2 * SB;         // 2*SB
    float* bc3     = (float*)(boff + 2 * SB);   // 3*96
    // align to 16B for bf16 weight arrays
    uintptr_t p = (uintptr_t)(bc3 + 3 * HF);
    p = (p + 15) & ~(uintptr_t)15;
    unsigned short* Whi3 = (unsigned short*)p;          // 3 * 96*288
    unsigned short* Wlo3 = Whi3 + 3 * HF * 288;         // 3 * 96*288
    uintptr_t p2 = (uintptr_t)(Wlo3 + 3 * HF * 288);
    p2 = (p2 + 15) & ~(uintptr_t)15;
    unsigned* g = (unsigned*)p2;

    hipMemsetAsync(cnt_dst, 0, (size_t)2 * N * sizeof(int), stream);
    hipMemsetAsync(g, 0, (size_t)GG * HF * sizeof(unsigned), stream);

    // weight prep (independent of graph build)
    const int prep_blocks = (HF * 288 + HF + 255) / 256;
    for (int l = 0; l < 3; l++)
        prep_kernel<<<prep_blocks, 256, 0, stream>>>(
            W[l][0], W[l][1], W[l][2], B[l][0], B[l][1], B[l][2],
            Whi3 + (long long)l * HF * 288, Wlo3 + (long long)l * HF * 288, bc3 + l * HF);

    const int CH = (N + SB - 1) / SB;
    count_kernel<<<(E + 255) / 256, 256, 0, stream>>>(ei, cnt_dst, cnt_src, slot_d, slot_s, E);
    scan_phase1<<<dim3(SB, 2), 256, 0, stream>>>(cnt_dst, cnt_src, off_dst, off_src, bsum, N, CH);
    scan_phase2<<<2, SB, 0, stream>>>(bsum, boff, off_dst, off_src, N);
    scan_phase3<<<dim3((N + 255) / 256, 2), 256, 0, stream>>>(off_dst, off_src, boff, N, CH);
    fill_kernel<<<(E + 255) / 256, 256, 0, stream>>>(ei, off_dst, off_src,
                                                     slot_d, slot_s, nbr_dst, nbr_src, E);

    const long long gather_threads = (long long)2 * N * 24;
    const int gather_blocks = (int)((gather_threads + 255) / 256);
    const int gemm_blocks = (N + 63) / 64;
    const int pool_blocks = (N + POOL_CHUNK - 1) / POOL_CHUNK;

    const float* cur_in = x;
    float* outs[3] = { hA, hB, hA };
    for (int l = 0; l < 3; l++) {
        gather_kernel<<<gather_blocks, 256, 0, stream>>>(
            cur_in, off_dst, nbr_dst, off_src, nbr_src, agg_sd, agg_ds, N);
        sage_mfma<<<gemm_blocks, 256, 0, stream>>>(
            cur_in, agg_sd, agg_ds,
            Whi3 + (long long)l * HF * 288, Wlo3 + (long long)l * HF * 288,
            bc3 + l * HF, outs[l], N);
        cur_in = outs[l];
    }

    pool_kernel<<<pool_blocks, 128, 0, stream>>>(outs[2], batch, g, N);
    mlp_kernel<<<1, 64, 0, stream>>>(g, lin1_w, lin1_b, lin2_w, lin2_b, (float*)d_out);
}